// Round 14
// baseline (102.881 us; speedup 1.0000x reference)
//
#include <hip/hip_runtime.h>

typedef __bf16 bf16x8 __attribute__((ext_vector_type(8)));
typedef float f32x4 __attribute__((ext_vector_type(4)));

#define TWO_LOG2E 2.88539008177792681f   // 2*log2(e): exp(2x) = exp2(x*TWO_LOG2E)

#define GLOADLDS16(g, l) __builtin_amdgcn_global_load_lds(                     \
    (const __attribute__((address_space(1))) void*)(g),                        \
    (__attribute__((address_space(3))) void*)(l), 16, 0, 0)

__device__ __forceinline__ unsigned f2bf(float f) {
    unsigned u = __float_as_uint(f);
    return (u + 0x7FFFu + ((u >> 16) & 1u)) >> 16;   // RNE
}

// ---------------- kernel 1: row-normalize z=[z1;z2] -> bf16 zn[8192][256] ---------------
__global__ void __launch_bounds__(256) normalize_kernel(
    const float* __restrict__ z1, const float* __restrict__ z2,
    unsigned short* __restrict__ zn, float* __restrict__ S, float* __restrict__ out)
{
    if (blockIdx.x < 32) S[(blockIdx.x << 8) + threadIdx.x] = 0.f;
    if (blockIdx.x == 32 && threadIdx.x == 0) out[0] = 0.f;

    const int wave = threadIdx.x >> 6, lane = threadIdx.x & 63;
    const int row = (blockIdx.x << 2) + wave;               // 2048 blocks * 4 rows
    const float* src = (row < 4096) ? (z1 + row * 256) : (z2 + (row - 4096) * 256);
    float4 v = ((const float4*)src)[lane];                  // 64 lanes * 4 = 256
    float ss = v.x * v.x + v.y * v.y + v.z * v.z + v.w * v.w;
#pragma unroll
    for (int m = 32; m > 0; m >>= 1) ss += __shfl_xor(ss, m, 64);
    float sc = 1.0f / fmaxf(sqrtf(ss), 1e-8f);
    uint2 w;
    w.x = f2bf(v.x * sc) | (f2bf(v.y * sc) << 16);
    w.y = f2bf(v.z * sc) | (f2bf(v.w * sc) << 16);
    *(uint2*)(zn + row * 256 + (lane << 2)) = w;
}

// ---------------- kernel 2: R8 body + DEPTH-3 parity staging, RING-8 (race-fixed) ------
// R13's 4-buffer depth-3 had a WAR race: stage(m+3) rewrote buffer (m-1)&3 inside the
// same barrier segment as other waves' consume(m-1) ds_reads (the infra failure meant
// it never ran; caught by audit). Ring-8 fixes it: stage(m+3) rewrites buffer (m+3)&7,
// last consumed as chunk m-5 (reads retired before barrier(m-4); stage issued after
// barrier(m-1) -> 4 barrier segments of WAR margin). Depth-3 schedule: prologue g0
// stages {0,2}, g1 stages {1}; at interval m, group (m+1)&1 stages chunk m+3 (3..30;
// tail m=28 stages 31), group m&1 waits OWN `s_waitcnt vmcnt(1)` (FIFO {m,m+2} ->
// chunk m complete), raw s_barrier publishes. Drains verified: g0 waits at even m,
// g1 at odd m; tail 1,1,0,0. NEVER __syncthreads mid-loop. LDS 32KB ring + 8KB
// colpart = 40KB -> 2 blocks/CU unchanged. Body/decode/reductions = R8 verbatim.
__global__ void __launch_bounds__(512, 4) simexp_kernel(
    const unsigned short* __restrict__ zn, float* __restrict__ S)
{
    __shared__ __align__(16) unsigned short Bs[8][2048];    // 8 x 4KB ring
    __shared__ float colpart[8][256];                       // per-wave col partials

    const int tid = threadIdx.x;
    const int wv = tid >> 6, lane = tid & 63;
    const int q = lane >> 4, n16 = lane & 15;
    const int g = wv >> 2, wl = wv & 3;         // staging group / quarter within group
    const int job = blockIdx.x;                 // 0..527

    int ti, tj;
    bool diag;
    if (job >= 496) {                           // diagonal tile
        ti = tj = job - 496;
        diag = true;
    } else {                                    // off-diag tile, ti<tj
        int t = 0, rem = job;
        while (rem >= 31 - t) { rem -= 31 - t; ++t; }   // uniform scan, <=31 iters
        ti = t; tj = t + 1 + rem;
        diag = false;
    }
    const int colTile = tj << 8;
    const int rowW = (ti << 8) + (wv << 5);     // this wave's 32 rows

    // A: 32 rows x K=256 in registers (frag: row=n16, k=q*8 within 32-elem step)
    bf16x8 a[2][8];
#pragma unroll
    for (int rt = 0; rt < 2; ++rt)
#pragma unroll
        for (int ks = 0; ks < 8; ++ks)
            a[rt][ks] = *(const bf16x8*)(zn + ((rowW + (rt << 4) + n16) << 8)
                                            + (ks << 5) + (q << 3));

    auto stage = [&](int m) {                   // 128B-contiguous rows (R3/R7 lesson)
        const int colBase = colTile + ((m >> 2) << 5);
        const int koff = (m & 3) << 6;
        unsigned short* base = &Bs[m & 7][0];
        int s = (wl << 6) + lane;               // 16B slot 0..255
        int c = s >> 3, d = s & 7;              // 8 consecutive lanes per row -> 128B
        int k8 = d ^ (c & 7);                   // XOR swizzle (conflict-free b128 reads)
        GLOADLDS16(zn + ((colBase + c) << 8) + koff + (k8 << 3), base + (s << 3));
    };

    float rs[2][4];
#pragma unroll
    for (int i = 0; i < 2; ++i)
#pragma unroll
        for (int j = 0; j < 4; ++j) rs[i][j] = 0.f;

    f32x4 acc[2][2];
    auto consume = [&](int buf, int kc) {       // buffer buf = m&7, k-chunk kc = m&3
        const unsigned short* bb = &Bs[buf][0];
#pragma unroll
        for (int ks = 0; ks < 2; ++ks) {
            bf16x8 bf[2];
#pragma unroll
            for (int ct = 0; ct < 2; ++ct) {
                int c  = (ct << 4) + n16;               // col 0..31
                int k8 = ((ks << 2) + q) ^ (c & 7);     // swizzled chunk
                bf[ct] = *(const bf16x8*)(bb + (((c << 3) + k8) << 3));
            }
#pragma unroll
            for (int rt = 0; rt < 2; ++rt)
#pragma unroll
                for (int ct = 0; ct < 2; ++ct)
                    acc[rt][ct] = __builtin_amdgcn_mfma_f32_16x16x32_bf16(
                        a[rt][(kc << 1) + ks], bf[ct], acc[rt][ct], 0, 0, 0);
        }
    };
    auto zacc = [&]() {
#pragma unroll
        for (int rt = 0; rt < 2; ++rt)
#pragma unroll
            for (int ct = 0; ct < 2; ++ct) acc[rt][ct] = (f32x4){0.f, 0.f, 0.f, 0.f};
    };
    auto epiC = [&](int cc) {                   // rows -> rs; cols -> colpart (off-diag)
        float cs[2] = {0.f, 0.f};
#pragma unroll
        for (int rt = 0; rt < 2; ++rt)
#pragma unroll
            for (int ct = 0; ct < 2; ++ct)
#pragma unroll
                for (int r = 0; r < 4; ++r) {
                    float e = __builtin_amdgcn_exp2f(acc[rt][ct][r] * TWO_LOG2E);
                    rs[rt][r] += e;
                    cs[ct] += e;
                }
        if (!diag) {                            // wave-uniform
#pragma unroll
            for (int ct = 0; ct < 2; ++ct) {
                float s = cs[ct];
                s += __shfl_xor(s, 16, 64);     // reduce over q
                s += __shfl_xor(s, 32, 64);
                if (lane < 16) colpart[wv][(cc << 5) + (ct << 4) + n16] = s;
            }
        }
    };

    // prologue: depth-3 (g0 stages even chunks 0,2 in FIFO order; g1 stages 1)
    if (g == 0) { stage(0); stage(2); } else { stage(1); }

    for (int cc = 0; cc < 7; ++cc) {            // intervals m=cc*4+kc, m=0..27
        zacc();
#pragma unroll
        for (int kc = 0; kc < 4; ++kc) {
            const int m = (cc << 2) + kc;
            if (((m + 1) & 1) == g) stage(m + 3);               // stages 3..30
            if ((m & 1) == g)                                   // chunk-m owner drains
                asm volatile("s_waitcnt vmcnt(1)" ::: "memory"); // {m,m+2} -> m done
            __builtin_amdgcn_s_barrier();
            asm volatile("" ::: "memory");      // keep ds_reads below the barrier
            consume(((cc & 1) << 2) | kc, kc);  // buffer m&7
        }
        epiC(cc);
    }
    // peeled tail cc=7 (cc&1=1 -> buffers 4..7): m=28..31, stage 31; drains 1,1,0,0
    zacc();
    if (g == 1) stage(31);                      // parity(31)=1
    if (g == 0) { asm volatile("s_waitcnt vmcnt(1)" ::: "memory"); }  // {28,30}->28
    __builtin_amdgcn_s_barrier();
    asm volatile("" ::: "memory");
    consume(4, 0);
    if (g == 1) { asm volatile("s_waitcnt vmcnt(1)" ::: "memory"); }  // {29,31}->29
    __builtin_amdgcn_s_barrier();
    asm volatile("" ::: "memory");
    consume(5, 1);
    if (g == 0) { asm volatile("s_waitcnt vmcnt(0)" ::: "memory"); }  // {30}->done
    __builtin_amdgcn_s_barrier();
    asm volatile("" ::: "memory");
    consume(6, 2);
    if (g == 1) { asm volatile("s_waitcnt vmcnt(0)" ::: "memory"); }  // {31}->done
    __builtin_amdgcn_s_barrier();
    asm volatile("" ::: "memory");
    consume(7, 3);
    epiC(7);

    // row flush (C/D layout: col=n16, row=q*4+r)
#pragma unroll
    for (int rt = 0; rt < 2; ++rt)
#pragma unroll
        for (int r = 0; r < 4; ++r) {
            float s = rs[rt][r];
            s += __shfl_xor(s, 1, 64);
            s += __shfl_xor(s, 2, 64);
            s += __shfl_xor(s, 4, 64);
            s += __shfl_xor(s, 8, 64);
            if (n16 == 0) atomicAdd(&S[rowW + (rt << 4) + (q << 2) + r], s);
        }

    // off-diag only: cross-wave col reduction, ONE atomic per column. vmcnt fully
    // drained above -> __syncthreads is safe here (publishes colpart writes).
    if (!diag) {
        __syncthreads();
        if (tid < 256) {
            float s = 0.f;
#pragma unroll
            for (int w = 0; w < 8; ++w) s += colpart[w][tid];
            atomicAdd(&S[colTile + tid], s);
        }
    }
}

// ---------------- kernel 3: loss = mean( log(S_i - e^{sim_ii}) - sim_{i,target} ) -------
__global__ void __launch_bounds__(256) finish_kernel(
    const unsigned short* __restrict__ zn, const float* __restrict__ S,
    float* __restrict__ out)
{
    __shared__ float vals[16];
    const int tid = threadIdx.x, lane = tid & 63, wave = tid >> 6;
    const int q = lane >> 4, n16 = lane & 15;
    const int rib = (wave << 2) + q;                // 0..15 rows per block
    const int row = (blockIdx.x << 4) + rib;        // 512 blocks * 16 rows
    const int tar = (row + 4096) & 8191;

    float drr = 0.f, drt = 0.f;
#pragma unroll
    for (int i = 0; i < 4; ++i) {
        int k = (i << 6) + (n16 << 2);
        uint2 ur = *(const uint2*)(zn + (row << 8) + k);
        uint2 ut = *(const uint2*)(zn + (tar << 8) + k);
        float a0 = __uint_as_float(ur.x << 16),  a1 = __uint_as_float(ur.x & 0xFFFF0000u);
        float a2 = __uint_as_float(ur.y << 16),  a3 = __uint_as_float(ur.y & 0xFFFF0000u);
        float b0 = __uint_as_float(ut.x << 16),  b1 = __uint_as_float(ut.x & 0xFFFF0000u);
        float b2 = __uint_as_float(ut.y << 16),  b3 = __uint_as_float(ut.y & 0xFFFF0000u);
        drr += a0 * a0 + a1 * a1 + a2 * a2 + a3 * a3;
        drt += a0 * b0 + a1 * b1 + a2 * b2 + a3 * b3;
    }
#pragma unroll
    for (int m = 1; m <= 8; m <<= 1) {
        drr += __shfl_xor(drr, m, 64);
        drt += __shfl_xor(drt, m, 64);
    }
    if (n16 == 0) {
        float Sv = S[row] - __builtin_amdgcn_exp2f(drr * TWO_LOG2E);  // remove diagonal
        vals[rib] = 0.693147180559945f * __builtin_amdgcn_logf(Sv) - 2.0f * drt;
    }
    __syncthreads();
    if (tid == 0) {
        float s = 0.f;
#pragma unroll
        for (int i = 0; i < 16; ++i) s += vals[i];
        atomicAdd(out, s * (1.0f / 8192.0f));
    }
}

extern "C" void kernel_launch(void* const* d_in, const int* in_sizes, int n_in,
                              void* d_out, int out_size, void* d_ws, size_t ws_size,
                              hipStream_t stream)
{
    const float* z1 = (const float*)d_in[0];
    const float* z2 = (const float*)d_in[1];
    unsigned short* zn = (unsigned short*)d_ws;                              // 4 MB
    float* S = (float*)((char*)d_ws + 8192 * 256 * sizeof(unsigned short));  // 32 KB
    float* out = (float*)d_out;

    normalize_kernel<<<2048, 256, 0, stream>>>(z1, z2, zn, S, out);
    simexp_kernel<<<528, 512, 0, stream>>>(zn, S);
    finish_kernel<<<512, 256, 0, stream>>>(zn, S, out);
}